// Round 1
// baseline (1169.848 us; speedup 1.0000x reference)
//
#include <hip/hip_runtime.h>

// Dims fixed by the problem: IN_CH=256, EDGE_DIM=64, H=4, C=32, H*C=128.

__device__ __forceinline__ float4 f4add(float4 a, float4 b) {
    return make_float4(a.x + b.x, a.y + b.y, a.z + b.z, a.w + b.w);
}

// K0: v[d][h] = sum_c W_edge[d,h*32+c] * att_edge[h,c]   (64x4, one block)
__global__ __launch_bounds__(256) void k_edge_vec(const float* __restrict__ W_edge,
                                                  const float* __restrict__ att_edge,
                                                  float* __restrict__ v) {
    int t = threadIdx.x;
    int d = t >> 2, h = t & 3;
    const float* wr = W_edge + d * 128 + h * 32;
    const float* ar = att_edge + h * 32;
    float s = 0.f;
#pragma unroll
    for (int c = 0; c < 32; ++c) s += wr[c] * ar[c];
    v[d * 4 + h] = s;
}

// K1: a_edge[e][h] = ea[e] . v[:,h]; also accumulate column-sum for a_loop.
// Wave handles 4 rows/iter: lane = (rq=row-in-quad)<<4 | sub; lane reads 4 cols.
__global__ __launch_bounds__(256) void k_a_edge(const float4* __restrict__ ea4,
                                                const float4* __restrict__ v4,
                                                float4* __restrict__ a_edge4,
                                                float* __restrict__ a_loop_sum,
                                                int E) {
    int tid = threadIdx.x;
    int lane = tid & 63;
    int sub = lane & 15, rq = lane >> 4;
    int wid = blockIdx.x * 4 + (tid >> 6);
    int nw = gridDim.x * 4;
    float4 v0 = v4[sub * 4 + 0], v1 = v4[sub * 4 + 1];
    float4 v2 = v4[sub * 4 + 2], v3 = v4[sub * 4 + 3];
    float4 asum = make_float4(0, 0, 0, 0);
    int nquad = (E + 3) >> 2;
    for (int qd = wid; qd < nquad; qd += nw) {
        int row = qd * 4 + rq;
        float4 p = make_float4(0, 0, 0, 0);
        bool valid = row < E;
        if (valid) {
            float4 ea = ea4[(size_t)row * 16 + sub];
            p.x = ea.x * v0.x + ea.y * v1.x + ea.z * v2.x + ea.w * v3.x;
            p.y = ea.x * v0.y + ea.y * v1.y + ea.z * v2.y + ea.w * v3.y;
            p.z = ea.x * v0.z + ea.y * v1.z + ea.z * v2.z + ea.w * v3.z;
            p.w = ea.x * v0.w + ea.y * v1.w + ea.z * v2.w + ea.w * v3.w;
            asum = f4add(asum, p);
        }
#pragma unroll
        for (int off = 1; off < 16; off <<= 1) {
            p.x += __shfl_xor(p.x, off);
            p.y += __shfl_xor(p.y, off);
            p.z += __shfl_xor(p.z, off);
            p.w += __shfl_xor(p.w, off);
        }
        if (valid && sub == 0) a_edge4[row] = p;
    }
    __shared__ float4 red[256];
    red[tid] = asum;
    __syncthreads();
    for (int s = 128; s > 0; s >>= 1) {
        if (tid < s) red[tid] = f4add(red[tid], red[tid + s]);
        __syncthreads();
    }
    if (tid == 0) {
        atomicAdd(&a_loop_sum[0], red[0].x);
        atomicAdd(&a_loop_sum[1], red[0].y);
        atomicAdd(&a_loop_sum[2], red[0].z);
        atomicAdd(&a_loop_sum[3], red[0].w);
    }
}

// K2: x_proj = x @ W  ([N,256]x[256,128]), fused a_src/a_dst dot products.
// Block: 32 rows x 128 cols; thread = (c4 = tid&31 -> 4 cols, rt = tid>>5 -> 4 rows).
__global__ __launch_bounds__(256) void k_gemm(const float* __restrict__ x,
                                              const float* __restrict__ W,
                                              const float* __restrict__ att_src,
                                              const float* __restrict__ att_dst,
                                              float* __restrict__ x_proj,
                                              float* __restrict__ a_src,
                                              float* __restrict__ a_dst,
                                              int N) {
    __shared__ float xs[32 * 64];    // 8 KB  (32 rows x 64 k)
    __shared__ float wsh[64 * 128];  // 32 KB (64 k x 128 cols)
    int tid = threadIdx.x;
    int row0 = blockIdx.x * 32;
    int c4 = tid & 31, rt = tid >> 5;
    int col0 = c4 * 4;
    float4 acc[4];
#pragma unroll
    for (int rr = 0; rr < 4; ++rr) acc[rr] = make_float4(0, 0, 0, 0);

    for (int kb = 0; kb < 256; kb += 64) {
#pragma unroll
        for (int i = 0; i < 2; ++i) {  // stage x tile: 32x64 = 512 float4
            int fi = tid + i * 256;
            int r = fi >> 4, cc = (fi & 15) * 4;
            int gr = row0 + r;
            if (gr >= N) gr = N - 1;
            float4 xv = *(const float4*)&x[(size_t)gr * 256 + kb + cc];
            *(float4*)&xs[r * 64 + cc] = xv;
        }
#pragma unroll
        for (int i = 0; i < 8; ++i) {  // stage W tile: 64x128 = 2048 float4
            int fi = tid + i * 256;
            int kr = fi >> 5, cc = (fi & 31) * 4;
            float4 wv = *(const float4*)&W[(size_t)(kb + kr) * 128 + cc];
            *(float4*)&wsh[kr * 128 + cc] = wv;
        }
        __syncthreads();
#pragma unroll
        for (int k4 = 0; k4 < 16; ++k4) {
            float4 xr[4], wv[4];
#pragma unroll
            for (int rr = 0; rr < 4; ++rr)
                xr[rr] = *(const float4*)&xs[(rt * 4 + rr) * 64 + k4 * 4];
#pragma unroll
            for (int ku = 0; ku < 4; ++ku)
                wv[ku] = *(const float4*)&wsh[(k4 * 4 + ku) * 128 + col0];
#pragma unroll
            for (int rr = 0; rr < 4; ++rr) {
                const float xk[4] = {xr[rr].x, xr[rr].y, xr[rr].z, xr[rr].w};
#pragma unroll
                for (int ku = 0; ku < 4; ++ku) {
                    acc[rr].x = fmaf(xk[ku], wv[ku].x, acc[rr].x);
                    acc[rr].y = fmaf(xk[ku], wv[ku].y, acc[rr].y);
                    acc[rr].z = fmaf(xk[ku], wv[ku].z, acc[rr].z);
                    acc[rr].w = fmaf(xk[ku], wv[ku].w, acc[rr].w);
                }
            }
        }
        __syncthreads();
    }
    float4 asw = *(const float4*)&att_src[col0];
    float4 adw = *(const float4*)&att_dst[col0];
    int head = c4 >> 3;
#pragma unroll
    for (int rr = 0; rr < 4; ++rr) {
        int r = row0 + rt * 4 + rr;
        if (r < N) *(float4*)&x_proj[(size_t)r * 128 + col0] = acc[rr];
        float ps = acc[rr].x * asw.x + acc[rr].y * asw.y + acc[rr].z * asw.z + acc[rr].w * asw.w;
        float pd = acc[rr].x * adw.x + acc[rr].y * adw.y + acc[rr].z * adw.z + acc[rr].w * adw.w;
#pragma unroll
        for (int off = 1; off < 8; off <<= 1) {
            ps += __shfl_xor(ps, off);
            pd += __shfl_xor(pd, off);
        }
        if ((c4 & 7) == 0 && r < N) {
            a_src[r * 4 + head] = ps;
            a_dst[r * 4 + head] = pd;
        }
    }
}

// K3: in-degree histogram (real edges only)
__global__ __launch_bounds__(256) void k_hist(const int* __restrict__ dst,
                                              int* __restrict__ counts, int E) {
    int i = blockIdx.x * blockDim.x + threadIdx.x;
    int stride = gridDim.x * blockDim.x;
    for (; i < E; i += stride) atomicAdd(&counts[dst[i]], 1);
}

// Scan step A: per-block (1024 elems) sums
__global__ __launch_bounds__(256) void k_scanA(const int* __restrict__ counts,
                                               int* __restrict__ bsum, int N) {
    int b = blockIdx.x, t = threadIdx.x;
    int i0 = b * 1024 + t * 4;
    int s = 0;
    if (i0 + 3 < N) {
        int4 c = *(const int4*)&counts[i0];
        s = c.x + c.y + c.z + c.w;
    } else {
        for (int j = 0; j < 4; ++j)
            if (i0 + j < N) s += counts[i0 + j];
    }
#pragma unroll
    for (int off = 32; off > 0; off >>= 1) s += __shfl_down(s, off);
    __shared__ int wsum[4];
    if ((t & 63) == 0) wsum[t >> 6] = s;
    __syncthreads();
    if (t == 0) bsum[b] = wsum[0] + wsum[1] + wsum[2] + wsum[3];
}

// Scan step B: exclusive scan of block sums (single block, NB <= 128)
__global__ __launch_bounds__(128) void k_scanB(const int* __restrict__ bsum,
                                               int* __restrict__ boff,
                                               int* __restrict__ row_ptr,
                                               int NB, int N) {
    __shared__ int sh[128];
    int t = threadIdx.x;
    int v = (t < NB) ? bsum[t] : 0;
    sh[t] = v;
    __syncthreads();
    for (int off = 1; off < 128; off <<= 1) {
        int val = sh[t];
        int add = (t >= off) ? sh[t - off] : 0;
        __syncthreads();
        sh[t] = val + add;
        __syncthreads();
    }
    int incl = sh[t];
    if (t < NB) boff[t] = incl - v;
    if (t == NB - 1) row_ptr[N] = incl;
}

// Scan step C: full exclusive scan -> row_ptr[0..N-1]
__global__ __launch_bounds__(256) void k_scanC(const int* __restrict__ counts,
                                               const int* __restrict__ boff,
                                               int* __restrict__ row_ptr, int N) {
    __shared__ int sh[256];
    int b = blockIdx.x, t = threadIdx.x;
    int i0 = b * 1024 + t * 4;
    int c[4];
    int ts = 0;
#pragma unroll
    for (int j = 0; j < 4; ++j) {
        c[j] = (i0 + j < N) ? counts[i0 + j] : 0;
        ts += c[j];
    }
    sh[t] = ts;
    __syncthreads();
    for (int off = 1; off < 256; off <<= 1) {
        int val = sh[t];
        int add = (t >= off) ? sh[t - off] : 0;
        __syncthreads();
        sh[t] = val + add;
        __syncthreads();
    }
    int run = sh[t] - ts + boff[b];
#pragma unroll
    for (int j = 0; j < 4; ++j) {
        if (i0 + j < N) row_ptr[i0 + j] = run;
        run += c[j];
    }
}

// K5: fill CSR: scatter src + exp(leakyrelu(alpha)) into per-dst slots
__global__ __launch_bounds__(256) void k_fill(const int* __restrict__ src,
                                              const int* __restrict__ dst,
                                              const float4* __restrict__ a_src4,
                                              const float4* __restrict__ a_dst4,
                                              const float4* __restrict__ a_edge4,
                                              const int* __restrict__ row_ptr,
                                              int* __restrict__ cursor,
                                              int* __restrict__ csr_src,
                                              float4* __restrict__ exp_csr, int E) {
    int i = blockIdx.x * blockDim.x + threadIdx.x;
    int stride = gridDim.x * blockDim.x;
    for (; i < E; i += stride) {
        int d = dst[i], s = src[i];
        int pos = row_ptr[d] + atomicAdd(&cursor[d], 1);
        csr_src[pos] = s;
        float4 a = a_src4[s], b = a_dst4[d], e = a_edge4[i];
        float4 r;
        float t;
        t = a.x + b.x + e.x; t = t > 0.f ? t : 0.2f * t; r.x = __expf(t);
        t = a.y + b.y + e.y; t = t > 0.f ? t : 0.2f * t; r.y = __expf(t);
        t = a.z + b.z + e.z; t = t > 0.f ? t : 0.2f * t; r.z = __expf(t);
        t = a.w + b.w + e.w; t = t > 0.f ? t : 0.2f * t; r.w = __expf(t);
        exp_csr[pos] = r;
    }
}

// K6: per-node wave: softmax denom + weighted gather-aggregate + bias
__global__ __launch_bounds__(256) void k_aggr(const float2* __restrict__ xp2,
                                              const int* __restrict__ row_ptr,
                                              const int* __restrict__ csr_src,
                                              const float* __restrict__ exp_csr,
                                              const float* __restrict__ a_src,
                                              const float* __restrict__ a_dst,
                                              const float* __restrict__ a_loop_sum,
                                              const float* __restrict__ bias,
                                              float* __restrict__ out,
                                              int N, float invE) {
    int lane = threadIdx.x & 63;
    int node = blockIdx.x * 4 + (threadIdx.x >> 6);
    if (node >= N) return;
    int head = lane >> 4;
    int st = row_ptr[node], en = row_ptr[node + 1];
    float aself = a_src[node * 4 + head] + a_dst[node * 4 + head] + a_loop_sum[head] * invE;
    aself = aself > 0.f ? aself : 0.2f * aself;
    float es = __expf(aself);
    float den = es;
    for (int p = st; p < en; ++p) den += exp_csr[(size_t)p * 4 + head];
    float inv = 1.f / den;
    float2 xv = xp2[(size_t)node * 64 + lane];
    float w0 = es * inv;
    float2 acc = make_float2(w0 * xv.x, w0 * xv.y);
    for (int p = st; p < en; ++p) {
        float w = exp_csr[(size_t)p * 4 + head] * inv;
        int s = csr_src[p];
        float2 q = xp2[(size_t)s * 64 + lane];
        acc.x = fmaf(w, q.x, acc.x);
        acc.y = fmaf(w, q.y, acc.y);
    }
    float2 bv = ((const float2*)bias)[lane];
    ((float2*)out)[(size_t)node * 64 + lane] = make_float2(acc.x + bv.x, acc.y + bv.y);
}

extern "C" void kernel_launch(void* const* d_in, const int* in_sizes, int n_in,
                              void* d_out, int out_size, void* d_ws, size_t ws_size,
                              hipStream_t stream) {
    const float* x = (const float*)d_in[0];
    const int* ei = (const int*)d_in[1];
    const float* ea = (const float*)d_in[2];
    const float* W = (const float*)d_in[3];
    const float* att_src = (const float*)d_in[4];
    const float* att_dst = (const float*)d_in[5];
    const float* W_edge = (const float*)d_in[6];
    const float* att_edge = (const float*)d_in[7];
    const float* bias = (const float*)d_in[8];
    float* out = (float*)d_out;

    const int N = in_sizes[0] / 256;
    const int E = in_sizes[1] / 2;
    const int* src = ei;
    const int* dst = ei + E;

    // ---- workspace carve (16B aligned) ----
    char* base = (char*)d_ws;
    size_t off = 0;
    auto carve = [&](size_t bytes) -> void* {
        off = (off + 15) & ~(size_t)15;
        void* p = base + off;
        off += bytes;
        return p;
    };
    float* a_loop_sum = (float*)carve(16);
    int* counts = (int*)carve((size_t)N * 4);
    int* cursor = (int*)carve((size_t)N * 4);
    size_t zero_bytes = off;  // everything above must start at 0
    float* v = (float*)carve(256 * 4);
    int* row_ptr = (int*)carve((size_t)(N + 1) * 4);
    int* bsum = (int*)carve(512);
    int* boff = (int*)carve(512);
    float* a_edge = (float*)carve((size_t)E * 16);
    float* x_proj = (float*)carve((size_t)N * 128 * 4);
    float* a_src = (float*)carve((size_t)N * 16);
    float* a_dst = (float*)carve((size_t)N * 16);
    int* csr_src = (int*)carve((size_t)E * 4);
    float* exp_csr = (float*)carve((size_t)E * 16);
    (void)ws_size;

    hipMemsetAsync(d_ws, 0, zero_bytes, stream);

    k_edge_vec<<<1, 256, 0, stream>>>(W_edge, att_edge, v);
    k_a_edge<<<1024, 256, 0, stream>>>((const float4*)ea, (const float4*)v,
                                       (float4*)a_edge, a_loop_sum, E);
    k_gemm<<<(N + 31) / 32, 256, 0, stream>>>(x, W, att_src, att_dst,
                                              x_proj, a_src, a_dst, N);
    k_hist<<<(E + 255) / 256, 256, 0, stream>>>(dst, counts, E);
    int NB = (N + 1023) / 1024;
    k_scanA<<<NB, 256, 0, stream>>>(counts, bsum, N);
    k_scanB<<<1, 128, 0, stream>>>(bsum, boff, row_ptr, NB, N);
    k_scanC<<<NB, 256, 0, stream>>>(counts, boff, row_ptr, N);
    k_fill<<<(E + 255) / 256, 256, 0, stream>>>(src, dst, (const float4*)a_src,
                                                (const float4*)a_dst, (const float4*)a_edge,
                                                row_ptr, cursor, csr_src,
                                                (float4*)exp_csr, E);
    k_aggr<<<(N + 3) / 4, 256, 0, stream>>>((const float2*)x_proj, row_ptr, csr_src,
                                            exp_csr, a_src, a_dst, a_loop_sum, bias,
                                            out, N, 1.0f / (float)E);
}

// Round 2
// 1054.553 us; speedup vs baseline: 1.1093x; 1.1093x over previous
//
#include <hip/hip_runtime.h>

// Dims fixed by the problem: IN_CH=256, EDGE_DIM=64, H=4, C=32, H*C=128.

struct __align__(16) Rec { float4 w; int4 meta; };  // meta.x = src node

__device__ __forceinline__ float4 f4add(float4 a, float4 b) {
    return make_float4(a.x + b.x, a.y + b.y, a.z + b.z, a.w + b.w);
}

// K0: v[d][h] = sum_c W_edge[d,h*32+c] * att_edge[h,c]   (64x4, one block)
__global__ __launch_bounds__(256) void k_edge_vec(const float* __restrict__ W_edge,
                                                  const float* __restrict__ att_edge,
                                                  float* __restrict__ v) {
    int t = threadIdx.x;
    int d = t >> 2, h = t & 3;
    const float* wr = W_edge + d * 128 + h * 32;
    const float* ar = att_edge + h * 32;
    float s = 0.f;
#pragma unroll
    for (int c = 0; c < 32; ++c) s += wr[c] * ar[c];
    v[d * 4 + h] = s;
}

// K1: a_edge[e][h] = ea[e] . v[:,h]; also accumulate column-sum for a_loop.
__global__ __launch_bounds__(256) void k_a_edge(const float4* __restrict__ ea4,
                                                const float4* __restrict__ v4,
                                                float4* __restrict__ a_edge4,
                                                float* __restrict__ a_loop_sum,
                                                int E) {
    int tid = threadIdx.x;
    int lane = tid & 63;
    int sub = lane & 15, rq = lane >> 4;
    int wid = blockIdx.x * 4 + (tid >> 6);
    int nw = gridDim.x * 4;
    float4 v0 = v4[sub * 4 + 0], v1 = v4[sub * 4 + 1];
    float4 v2 = v4[sub * 4 + 2], v3 = v4[sub * 4 + 3];
    float4 asum = make_float4(0, 0, 0, 0);
    int nquad = (E + 3) >> 2;
    for (int qd = wid; qd < nquad; qd += nw) {
        int row = qd * 4 + rq;
        float4 p = make_float4(0, 0, 0, 0);
        bool valid = row < E;
        if (valid) {
            float4 ea = ea4[(size_t)row * 16 + sub];
            p.x = ea.x * v0.x + ea.y * v1.x + ea.z * v2.x + ea.w * v3.x;
            p.y = ea.x * v0.y + ea.y * v1.y + ea.z * v2.y + ea.w * v3.y;
            p.z = ea.x * v0.z + ea.y * v1.z + ea.z * v2.z + ea.w * v3.z;
            p.w = ea.x * v0.w + ea.y * v1.w + ea.z * v2.w + ea.w * v3.w;
            asum = f4add(asum, p);
        }
#pragma unroll
        for (int off = 1; off < 16; off <<= 1) {
            p.x += __shfl_xor(p.x, off);
            p.y += __shfl_xor(p.y, off);
            p.z += __shfl_xor(p.z, off);
            p.w += __shfl_xor(p.w, off);
        }
        if (valid && sub == 0) a_edge4[row] = p;
    }
    __shared__ float4 red[256];
    red[tid] = asum;
    __syncthreads();
    for (int s = 128; s > 0; s >>= 1) {
        if (tid < s) red[tid] = f4add(red[tid], red[tid + s]);
        __syncthreads();
    }
    if (tid == 0) {
        atomicAdd(&a_loop_sum[0], red[0].x);
        atomicAdd(&a_loop_sum[1], red[0].y);
        atomicAdd(&a_loop_sum[2], red[0].z);
        atomicAdd(&a_loop_sum[3], red[0].w);
    }
}

// K2: x_proj = x @ W  ([N,256]x[256,128]), fused a_src/a_dst dot products.
__global__ __launch_bounds__(256) void k_gemm(const float* __restrict__ x,
                                              const float* __restrict__ W,
                                              const float* __restrict__ att_src,
                                              const float* __restrict__ att_dst,
                                              float* __restrict__ x_proj,
                                              float* __restrict__ a_src,
                                              float* __restrict__ a_dst,
                                              int N) {
    __shared__ float xs[32 * 64];    // 8 KB  (32 rows x 64 k)
    __shared__ float wsh[64 * 128];  // 32 KB (64 k x 128 cols)
    int tid = threadIdx.x;
    int row0 = blockIdx.x * 32;
    int c4 = tid & 31, rt = tid >> 5;
    int col0 = c4 * 4;
    float4 acc[4];
#pragma unroll
    for (int rr = 0; rr < 4; ++rr) acc[rr] = make_float4(0, 0, 0, 0);

    for (int kb = 0; kb < 256; kb += 64) {
#pragma unroll
        for (int i = 0; i < 2; ++i) {
            int fi = tid + i * 256;
            int r = fi >> 4, cc = (fi & 15) * 4;
            int gr = row0 + r;
            if (gr >= N) gr = N - 1;
            float4 xv = *(const float4*)&x[(size_t)gr * 256 + kb + cc];
            *(float4*)&xs[r * 64 + cc] = xv;
        }
#pragma unroll
        for (int i = 0; i < 8; ++i) {
            int fi = tid + i * 256;
            int kr = fi >> 5, cc = (fi & 31) * 4;
            float4 wv = *(const float4*)&W[(size_t)(kb + kr) * 128 + cc];
            *(float4*)&wsh[kr * 128 + cc] = wv;
        }
        __syncthreads();
#pragma unroll
        for (int k4 = 0; k4 < 16; ++k4) {
            float4 xr[4], wv[4];
#pragma unroll
            for (int rr = 0; rr < 4; ++rr)
                xr[rr] = *(const float4*)&xs[(rt * 4 + rr) * 64 + k4 * 4];
#pragma unroll
            for (int ku = 0; ku < 4; ++ku)
                wv[ku] = *(const float4*)&wsh[(k4 * 4 + ku) * 128 + col0];
#pragma unroll
            for (int rr = 0; rr < 4; ++rr) {
                const float xk[4] = {xr[rr].x, xr[rr].y, xr[rr].z, xr[rr].w};
#pragma unroll
                for (int ku = 0; ku < 4; ++ku) {
                    acc[rr].x = fmaf(xk[ku], wv[ku].x, acc[rr].x);
                    acc[rr].y = fmaf(xk[ku], wv[ku].y, acc[rr].y);
                    acc[rr].z = fmaf(xk[ku], wv[ku].z, acc[rr].z);
                    acc[rr].w = fmaf(xk[ku], wv[ku].w, acc[rr].w);
                }
            }
        }
        __syncthreads();
    }
    float4 asw = *(const float4*)&att_src[col0];
    float4 adw = *(const float4*)&att_dst[col0];
    int head = c4 >> 3;
#pragma unroll
    for (int rr = 0; rr < 4; ++rr) {
        int r = row0 + rt * 4 + rr;
        if (r < N) *(float4*)&x_proj[(size_t)r * 128 + col0] = acc[rr];
        float ps = acc[rr].x * asw.x + acc[rr].y * asw.y + acc[rr].z * asw.z + acc[rr].w * asw.w;
        float pd = acc[rr].x * adw.x + acc[rr].y * adw.y + acc[rr].z * adw.z + acc[rr].w * adw.w;
#pragma unroll
        for (int off = 1; off < 8; off <<= 1) {
            ps += __shfl_xor(ps, off);
            pd += __shfl_xor(pd, off);
        }
        if ((c4 & 7) == 0 && r < N) {
            a_src[r * 4 + head] = ps;
            a_dst[r * 4 + head] = pd;
        }
    }
}

// K3: in-degree histogram (real edges only)
__global__ __launch_bounds__(256) void k_hist(const int* __restrict__ dst,
                                              int* __restrict__ counts, int E) {
    int i = blockIdx.x * blockDim.x + threadIdx.x;
    int stride = gridDim.x * blockDim.x;
    for (; i < E; i += stride) atomicAdd(&counts[dst[i]], 1);
}

// Scan step A: per-block (1024 elems) sums
__global__ __launch_bounds__(256) void k_scanA(const int* __restrict__ counts,
                                               int* __restrict__ bsum, int N) {
    int b = blockIdx.x, t = threadIdx.x;
    int i0 = b * 1024 + t * 4;
    int s = 0;
    if (i0 + 3 < N) {
        int4 c = *(const int4*)&counts[i0];
        s = c.x + c.y + c.z + c.w;
    } else {
        for (int j = 0; j < 4; ++j)
            if (i0 + j < N) s += counts[i0 + j];
    }
#pragma unroll
    for (int off = 32; off > 0; off >>= 1) s += __shfl_down(s, off);
    __shared__ int wsum[4];
    if ((t & 63) == 0) wsum[t >> 6] = s;
    __syncthreads();
    if (t == 0) bsum[b] = wsum[0] + wsum[1] + wsum[2] + wsum[3];
}

// Scan step B: exclusive scan of block sums (single block, NB <= 128)
__global__ __launch_bounds__(128) void k_scanB(const int* __restrict__ bsum,
                                               int* __restrict__ boff,
                                               int* __restrict__ row_ptr,
                                               int NB, int N) {
    __shared__ int sh[128];
    int t = threadIdx.x;
    int v = (t < NB) ? bsum[t] : 0;
    sh[t] = v;
    __syncthreads();
    for (int off = 1; off < 128; off <<= 1) {
        int val = sh[t];
        int add = (t >= off) ? sh[t - off] : 0;
        __syncthreads();
        sh[t] = val + add;
        __syncthreads();
    }
    int incl = sh[t];
    if (t < NB) boff[t] = incl - v;
    if (t == NB - 1) row_ptr[N] = incl;
}

// Scan step C: full exclusive scan -> row_ptr[0..N-1]
__global__ __launch_bounds__(256) void k_scanC(const int* __restrict__ counts,
                                               const int* __restrict__ boff,
                                               int* __restrict__ row_ptr, int N) {
    __shared__ int sh[256];
    int b = blockIdx.x, t = threadIdx.x;
    int i0 = b * 1024 + t * 4;
    int c[4];
    int ts = 0;
#pragma unroll
    for (int j = 0; j < 4; ++j) {
        c[j] = (i0 + j < N) ? counts[i0 + j] : 0;
        ts += c[j];
    }
    sh[t] = ts;
    __syncthreads();
    for (int off = 1; off < 256; off <<= 1) {
        int val = sh[t];
        int add = (t >= off) ? sh[t - off] : 0;
        __syncthreads();
        sh[t] = val + add;
        __syncthreads();
    }
    int run = sh[t] - ts + boff[b];
#pragma unroll
    for (int j = 0; j < 4; ++j) {
        if (i0 + j < N) row_ptr[i0 + j] = run;
        run += c[j];
    }
}

// K5: fill CSR: one packed 32B record per edge {w=exp(lrelu(alpha)), src}
__global__ __launch_bounds__(256) void k_fill(const int* __restrict__ src,
                                              const int* __restrict__ dst,
                                              const float4* __restrict__ a_src4,
                                              const float4* __restrict__ a_dst4,
                                              const float4* __restrict__ a_edge4,
                                              const int* __restrict__ row_ptr,
                                              int* __restrict__ cursor,
                                              Rec* __restrict__ recs, int E) {
    int i = blockIdx.x * blockDim.x + threadIdx.x;
    int stride = gridDim.x * blockDim.x;
    for (; i < E; i += stride) {
        int d = dst[i], s = src[i];
        int pos = row_ptr[d] + atomicAdd(&cursor[d], 1);
        float4 a = a_src4[s], b = a_dst4[d], e = a_edge4[i];
        float4 r;
        float t;
        t = a.x + b.x + e.x; t = t > 0.f ? t : 0.2f * t; r.x = __expf(t);
        t = a.y + b.y + e.y; t = t > 0.f ? t : 0.2f * t; r.y = __expf(t);
        t = a.z + b.z + e.z; t = t > 0.f ? t : 0.2f * t; r.z = __expf(t);
        t = a.w + b.w + e.w; t = t > 0.f ? t : 0.2f * t; r.w = __expf(t);
        recs[pos].w = r;
        recs[pos].meta = make_int4(s, 0, 0, 0);
    }
}

// K6: per-node wave: fused single-pass weighted gather + denom + bias.
// Unnormalized accumulate: acc = sum w*x, den = sum w; out = acc/den + bias.
__global__ __launch_bounds__(256) void k_aggr(const float2* __restrict__ xp2,
                                              const int* __restrict__ row_ptr,
                                              const Rec* __restrict__ recs,
                                              const float* __restrict__ a_src,
                                              const float* __restrict__ a_dst,
                                              const float* __restrict__ a_loop_sum,
                                              const float* __restrict__ bias,
                                              float* __restrict__ out,
                                              int N, float invE) {
    int lane = threadIdx.x & 63;
    int node = blockIdx.x * 4 + (threadIdx.x >> 6);
    if (node >= N) return;
    int head = lane >> 4;
    int st = row_ptr[node], en = row_ptr[node + 1];
    float den = 0.f;
    float2 acc = make_float2(0.f, 0.f);
    int p = st;
    // 4-wide: 4 independent gathers in flight
    for (; p + 4 <= en; p += 4) {
        const float* r0 = (const float*)&recs[p];
        const float* r1 = (const float*)&recs[p + 1];
        const float* r2 = (const float*)&recs[p + 2];
        const float* r3 = (const float*)&recs[p + 3];
        float w0 = r0[head], w1 = r1[head], w2 = r2[head], w3 = r3[head];
        int s0 = ((const int*)r0)[4];
        int s1 = ((const int*)r1)[4];
        int s2 = ((const int*)r2)[4];
        int s3 = ((const int*)r3)[4];
        float2 q0 = xp2[(size_t)s0 * 64 + lane];
        float2 q1 = xp2[(size_t)s1 * 64 + lane];
        float2 q2 = xp2[(size_t)s2 * 64 + lane];
        float2 q3 = xp2[(size_t)s3 * 64 + lane];
        acc.x = fmaf(w0, q0.x, acc.x); acc.y = fmaf(w0, q0.y, acc.y);
        acc.x = fmaf(w1, q1.x, acc.x); acc.y = fmaf(w1, q1.y, acc.y);
        acc.x = fmaf(w2, q2.x, acc.x); acc.y = fmaf(w2, q2.y, acc.y);
        acc.x = fmaf(w3, q3.x, acc.x); acc.y = fmaf(w3, q3.y, acc.y);
        den += (w0 + w1) + (w2 + w3);
    }
    for (; p < en; ++p) {
        const float* r0 = (const float*)&recs[p];
        float w = r0[head];
        int s = ((const int*)r0)[4];
        float2 q = xp2[(size_t)s * 64 + lane];
        acc.x = fmaf(w, q.x, acc.x); acc.y = fmaf(w, q.y, acc.y);
        den += w;
    }
    // analytic self-loop (loop edge_attr = column mean => logit = mean of a_edge)
    float aself = a_src[node * 4 + head] + a_dst[node * 4 + head] + a_loop_sum[head] * invE;
    aself = aself > 0.f ? aself : 0.2f * aself;
    float es = __expf(aself);
    den += es;
    float2 xv = xp2[(size_t)node * 64 + lane];
    acc.x = fmaf(es, xv.x, acc.x);
    acc.y = fmaf(es, xv.y, acc.y);
    float inv = 1.f / den;
    float2 bv = ((const float2*)bias)[lane];
    ((float2*)out)[(size_t)node * 64 + lane] =
        make_float2(fmaf(acc.x, inv, bv.x), fmaf(acc.y, inv, bv.y));
}

extern "C" void kernel_launch(void* const* d_in, const int* in_sizes, int n_in,
                              void* d_out, int out_size, void* d_ws, size_t ws_size,
                              hipStream_t stream) {
    const float* x = (const float*)d_in[0];
    const int* ei = (const int*)d_in[1];
    const float* ea = (const float*)d_in[2];
    const float* W = (const float*)d_in[3];
    const float* att_src = (const float*)d_in[4];
    const float* att_dst = (const float*)d_in[5];
    const float* W_edge = (const float*)d_in[6];
    const float* att_edge = (const float*)d_in[7];
    const float* bias = (const float*)d_in[8];
    float* out = (float*)d_out;

    const int N = in_sizes[0] / 256;
    const int E = in_sizes[1] / 2;
    const int* src = ei;
    const int* dst = ei + E;

    // ---- workspace carve (16B aligned) ----
    char* base = (char*)d_ws;
    size_t off = 0;
    auto carve = [&](size_t bytes) -> void* {
        off = (off + 15) & ~(size_t)15;
        void* p = base + off;
        off += bytes;
        return p;
    };
    float* a_loop_sum = (float*)carve(16);
    int* counts = (int*)carve((size_t)N * 4);
    int* cursor = (int*)carve((size_t)N * 4);
    size_t zero_bytes = off;  // everything above must start at 0
    float* v = (float*)carve(256 * 4);
    int* row_ptr = (int*)carve((size_t)(N + 1) * 4);
    int* bsum = (int*)carve(512);
    int* boff = (int*)carve(512);
    float* a_edge = (float*)carve((size_t)E * 16);
    float* x_proj = (float*)carve((size_t)N * 128 * 4);
    float* a_src = (float*)carve((size_t)N * 16);
    float* a_dst = (float*)carve((size_t)N * 16);
    Rec* recs = (Rec*)carve((size_t)E * sizeof(Rec));
    (void)ws_size;

    hipMemsetAsync(d_ws, 0, zero_bytes, stream);

    k_edge_vec<<<1, 256, 0, stream>>>(W_edge, att_edge, v);
    k_a_edge<<<1024, 256, 0, stream>>>((const float4*)ea, (const float4*)v,
                                       (float4*)a_edge, a_loop_sum, E);
    k_gemm<<<(N + 31) / 32, 256, 0, stream>>>(x, W, att_src, att_dst,
                                              x_proj, a_src, a_dst, N);
    k_hist<<<(E + 255) / 256, 256, 0, stream>>>(dst, counts, E);
    int NB = (N + 1023) / 1024;
    k_scanA<<<NB, 256, 0, stream>>>(counts, bsum, N);
    k_scanB<<<1, 128, 0, stream>>>(bsum, boff, row_ptr, NB, N);
    k_scanC<<<NB, 256, 0, stream>>>(counts, boff, row_ptr, N);
    k_fill<<<(E + 255) / 256, 256, 0, stream>>>(src, dst, (const float4*)a_src,
                                                (const float4*)a_dst, (const float4*)a_edge,
                                                row_ptr, cursor, recs, E);
    k_aggr<<<(N + 3) / 4, 256, 0, stream>>>((const float2*)x_proj, row_ptr, recs,
                                            a_src, a_dst, a_loop_sum, bias,
                                            out, N, 1.0f / (float)E);
}